// Round 2
// 4006.301 us; speedup vs baseline: 1.3542x; 1.3542x over previous
//
#include <hip/hip_runtime.h>
#include <math.h>

#define N_NODES 10000
#define N_EDGES 100000
#define NB      64
#define EMB     100
#define H       2000
#define LAYERS  4

#define C1_OC 50
#define C1_L  666
#define C2_OC 100
#define C2_L  221
#define C3_OC 150
#define C3_L  73
#define LIN1_IN  10950
#define LIN1_OUT 500

// fp16 GEMM geometry (K padded to 64-aligned halves for the 8-phase GRU kernel)
#define SEG  2048          // K = H padded to 2048 (BK-aligned)
#define MP   10240         // M = N_NODES padded to 256
#define NW   2048          // Wg output cols padded
#define KK2  4096          // concat K for GRU ([Agg | Hc]), halves of 2048
#define NPACK 8192         // 4 gates * 2048 h-cols, packed for the 256-tile GRU kernel
#define NT   (KK2 / 64)    // 64 K-tiles

using half8 = __attribute__((ext_vector_type(8))) _Float16;
using f32x4 = __attribute__((ext_vector_type(4))) float;

__device__ inline void gload16(const void* g, void* l) {
  __builtin_amdgcn_global_load_lds(
      (const __attribute__((address_space(1))) unsigned int*)g,
      (__attribute__((address_space(3))) unsigned int*)l, 16, 0, 0);
}

// ---------------- embedding -> fp16 h ----------------
__global__ void embed16_kernel(const int* __restrict__ tokens,
                               const float* __restrict__ table,
                               _Float16* __restrict__ h) {
  int n = blockIdx.x;
  int tok = tokens[n];
  for (int c = threadIdx.x; c < SEG; c += 256) {
    float v = (c < EMB) ? table[tok * EMB + c] : 0.f;
    h[(size_t)n * SEG + c] = (_Float16)v;
  }
}

// ---------------- CSR build ----------------
__global__ void hist_kernel(const int* __restrict__ dst, int* __restrict__ counts, int e) {
  int i = blockIdx.x * 256 + threadIdx.x;
  if (i < e) atomicAdd(&counts[dst[i]], 1);
}

__global__ void scan_kernel(const int* __restrict__ counts, int* __restrict__ row_off, int n) {
  __shared__ int sums[1024];
  int tid = threadIdx.x;
  const int CH = (n + 1023) / 1024;
  int start = tid * CH;
  int local = 0;
  for (int i = 0; i < CH; i++)
    if (start + i < n) local += counts[start + i];
  sums[tid] = local;
  __syncthreads();
  for (int off = 1; off < 1024; off <<= 1) {
    int v = (tid >= off) ? sums[tid - off] : 0;
    __syncthreads();
    sums[tid] += v;
    __syncthreads();
  }
  int run = (tid > 0) ? sums[tid - 1] : 0;
  for (int i = 0; i < CH; i++)
    if (start + i < n) { row_off[start + i] = run; run += counts[start + i]; }
  if (tid == 1023) row_off[n] = run;
}

__global__ void scatter_kernel(const int* __restrict__ src, const int* __restrict__ dst,
                               const int* __restrict__ row_off, int* __restrict__ cursor,
                               int* __restrict__ csr_src, int e) {
  int i = blockIdx.x * 256 + threadIdx.x;
  if (i < e) {
    int d = dst[i];
    int pos = atomicAdd(&cursor[d], 1);
    csr_src[row_off[d] + pos] = src[i];
  }
}

__global__ void starts_kernel(const int* __restrict__ batch, int* __restrict__ starts, int n) {
  int i = blockIdx.x * 256 + threadIdx.x;
  if (i >= n) return;
  int b = batch[i];
  int pb = (i == 0) ? -1 : batch[i - 1];
  if (b != pb)
    for (int x = pb + 1; x <= b; x++) starts[x] = i;
  if (i == n - 1)
    for (int x = b + 1; x <= NB; x++) starts[x] = n;
}

// ---------------- weight prep ----------------
// W_ggc[l] (H x H) -> transposed fp16 Bt: out[l][n][k] = W[k][n], n<NW, k<SEG
__global__ void prep_wg16_kernel(const float* __restrict__ Wg, _Float16* __restrict__ out) {
  __shared__ float t[32][33];
  int l = blockIdx.z;
  const float* W = Wg + (size_t)l * H * H;
  _Float16* o = out + (size_t)l * NW * SEG;
  int kt = blockIdx.x * 32, nt = blockIdx.y * 32;
  int tx = threadIdx.x & 31, ty = threadIdx.x >> 5;  // ty 0..7
#pragma unroll
  for (int i = 0; i < 4; i++) {
    int k = kt + ty + i * 8, n = nt + tx;
    t[tx][ty + i * 8] = (k < H && n < H) ? W[(size_t)k * H + n] : 0.f;
  }
  __syncthreads();
#pragma unroll
  for (int i = 0; i < 4; i++) {
    int nl = ty + i * 8, kl = tx;
    o[(size_t)(nt + nl) * SEG + (kt + kl)] = (_Float16)t[nl][kl];
  }
}

// Packed GRU weight matrix Wp: NPACK rows x KK2 cols, laid out for the 256-tile
// 8-phase kernel. Row n decomposition (within a 256-row block):
//   nh = (n>>7)&1, WN = (n>>5)&3, j = (n>>4)&1, fr = n&15
//   gate(n) = nh*2 + j        (0=r, 1=z, 2=inn, 3=hn)
//   hcol(n) = (n>>8)*64 + WN*16 + fr
// gate0 (r): [Wih_r | Whh_r]; gate1 (z): [Wih_z | Whh_z]
// gate2 (inn): [Wih_n | 0];   gate3 (hn): [0 | Whh_n]
__global__ void prep_wpack_kernel(const float* __restrict__ Wih, const float* __restrict__ Whh,
                                  _Float16* __restrict__ out) {
  int n = blockIdx.y;
  int k = blockIdx.x * 256 + threadIdx.x;
  if (k >= KK2) return;
  int gate = ((n >> 7) & 1) * 2 + ((n >> 4) & 1);
  int hcol = (n >> 8) * 64 + ((n >> 5) & 3) * 16 + (n & 15);
  float v = 0.f;
  if (hcol < H) {
    if (gate < 2) {
      int row = gate * H + hcol;
      if (k < 2048) { if (k < H) v = Wih[(size_t)row * H + k]; }
      else { int k2 = k - 2048; if (k2 < H) v = Whh[(size_t)row * H + k2]; }
    } else if (gate == 2) {
      if (k < H) v = Wih[(size_t)(2 * H + hcol) * H + k];
    } else {
      int k2 = k - 2048;
      if (k2 >= 0 && k2 < H) v = Whh[(size_t)(2 * H + hcol) * H + k2];
    }
  }
  out[(size_t)n * KK2 + k] = (_Float16)v;
}

// ---------------- fp16 GEMM: C[m][n] = sum_k A[m][k] * Bt[n][k], fp16 out ----------------
__global__ __launch_bounds__(256) void gemm16_kernel(
    const _Float16* __restrict__ A, const _Float16* __restrict__ Bt,
    _Float16* __restrict__ C) {
  __shared__ __align__(16) _Float16 As[128][32];
  __shared__ __align__(16) _Float16 Bs[128][32];
  const int tid = threadIdx.x;
  const int wave = tid >> 6, lane = tid & 63;
  const int bm = blockIdx.y * 128, bn = blockIdx.x * 128;
  const int wm = (wave & 1) * 64, wn = (wave >> 1) * 64;
  const int srow = lane >> 2, scol = (lane & 3) * 8;
  const int fr = lane & 15, quad = lane >> 4;

  f32x4 acc[4][4];
#pragma unroll
  for (int i = 0; i < 4; i++)
#pragma unroll
    for (int j = 0; j < 4; j++) {
      f32x4 z = {0.f, 0.f, 0.f, 0.f};
      acc[i][j] = z;
    }

  for (int k0 = 0; k0 < SEG; k0 += 32) {
    gload16(A + (size_t)(bm + wave * 32 + srow) * SEG + k0 + scol, &As[wave * 32][0]);
    gload16(A + (size_t)(bm + wave * 32 + 16 + srow) * SEG + k0 + scol, &As[wave * 32 + 16][0]);
    gload16(Bt + (size_t)(bn + wave * 32 + srow) * SEG + k0 + scol, &Bs[wave * 32][0]);
    gload16(Bt + (size_t)(bn + wave * 32 + 16 + srow) * SEG + k0 + scol, &Bs[wave * 32 + 16][0]);
    __syncthreads();
    half8 af[4], bf[4];
#pragma unroll
    for (int i = 0; i < 4; i++) {
      af[i] = *(const half8*)&As[wm + i * 16 + fr][quad * 8];
      bf[i] = *(const half8*)&Bs[wn + i * 16 + fr][quad * 8];
    }
#pragma unroll
    for (int i = 0; i < 4; i++)
#pragma unroll
      for (int j = 0; j < 4; j++)
        acc[i][j] = __builtin_amdgcn_mfma_f32_16x16x32_f16(af[i], bf[j], acc[i][j], 0, 0, 0);
    __syncthreads();
  }
#pragma unroll
  for (int i = 0; i < 4; i++)
#pragma unroll
    for (int j = 0; j < 4; j++) {
      int n = bn + wn + j * 16 + fr;
      if (n >= SEG) continue;
#pragma unroll
      for (int r = 0; r < 4; r++) {
        int m = bm + wm + i * 16 + quad * 4 + r;
        C[(size_t)m * SEG + n] = (_Float16)acc[i][j][r];
      }
    }
}

// ---------------- edge aggregation on fp16 m, fp32 accumulate, fp16 out ----------------
__global__ void agg16_kernel(const _Float16* __restrict__ m, const int* __restrict__ row_off,
                             const int* __restrict__ csr_src, _Float16* __restrict__ agg) {
  int node = blockIdx.x;
  int s = row_off[node], e = row_off[node + 1];
  int tid = threadIdx.x;
  bool act = tid < (SEG / 8);   // 256 -> all active
  float a[8] = {0, 0, 0, 0, 0, 0, 0, 0};
  __shared__ int s_src[256];
  for (int base = s; base < e; base += 256) {
    int cnt = min(256, e - base);
    __syncthreads();
    if (tid < cnt) s_src[tid] = csr_src[base + tid];
    __syncthreads();
    for (int p = 0; p < cnt; p++) {
      if (act) {
        half8 v = *(const half8*)&m[(size_t)s_src[p] * SEG + tid * 8];
#pragma unroll
        for (int i = 0; i < 8; i++) a[i] += (float)v[i];
      }
    }
  }
  if (act) {
    half8 o;
#pragma unroll
    for (int i = 0; i < 8; i++) o[i] = (_Float16)a[i];
    *(half8*)&agg[(size_t)node * SEG + tid * 8] = o;
  }
}

// ---------------- fused GRU: 256x256-tile 8-phase pipelined GEMM + local epilogue --------
// A-virtual = [Agg | Hc] (M x 4096); B = Wp (8192 x 4096).
// 512 threads = 8 waves (2 M-halves x 4 N-quarters). Per lane: h-col
// c = bx*64 + WN*16 + fr; acc gates g = nh*2 + j.
// LDS: double-buffered A/B tiles [256][64] f16, XOR-swizzled 16B clusters
// (cluster ^= row&7) via pre-swizzled global source + swizzled ds_read.
// Schedule per K-tile: 4 phases {ds_read subtile | 1 half-tile prefetch issue |
// s_barrier | lgkmcnt(0) | setprio(1) MFMA setprio(0) | s_barrier}, counted
// vmcnt(4) once per tile (never 0 in steady state).
__global__ __launch_bounds__(512, 2) void gru8p_kernel(
    const _Float16* __restrict__ Agg, const _Float16* __restrict__ Hc,
    const _Float16* __restrict__ Wp,
    const float* __restrict__ b_ih, const float* __restrict__ b_hh,
    _Float16* __restrict__ Hn) {
  __shared__ __align__(16) _Float16 As[2][256][64];   // 64 KiB
  __shared__ __align__(16) _Float16 Bs[2][256][64];   // 64 KiB
  const int tid = threadIdx.x;
  const int wave = tid >> 6, lane = tid & 63;
  const int WM = wave >> 2, WN = wave & 3;
  const int fr = lane & 15, quad = lane >> 4;
  const int bm = blockIdx.y * 256, bn = blockIdx.x * 256;

  // staging: per gload call, wave w covers rows [w*8, w*8+8); lane -> row w*8+(lane>>3),
  // 16B cluster lane&7. Source cluster pre-swizzled with ^(row&7) = ^(lane>>3).
  const int sr = lane >> 3;
  const int scl = (lane & 7) ^ sr;

  auto stageA = [&](int buf, int hf, int t) {
    const _Float16* base = (t < 32) ? Agg : Hc;
    const int k0 = (t & 31) * 64;
    const int r0 = hf * 128 + wave * 8 + sr;
#pragma unroll
    for (int c2 = 0; c2 < 2; c2++) {
      gload16(base + (size_t)(bm + r0 + c2 * 64) * SEG + k0 + scl * 8,
              &As[buf][hf * 128 + c2 * 64 + wave * 8][0]);
    }
  };
  auto stageB = [&](int buf, int hf, int t) {
    const int k0 = t * 64;
    const int r0 = hf * 128 + wave * 8 + sr;
#pragma unroll
    for (int c2 = 0; c2 < 2; c2++) {
      gload16(Wp + (size_t)(bn + r0 + c2 * 64) * KK2 + k0 + scl * 8,
              &Bs[buf][hf * 128 + c2 * 64 + wave * 8][0]);
    }
  };

  // swizzled fragment-read clusters (row&7 == fr&7 for all fragment rows)
  const int x0 = ((quad ^ (fr & 7)) << 3);        // ks=0 halves offset
  const int x1 = (((quad + 4) ^ (fr & 7)) << 3);  // ks=1

  auto ldsA = [&](int buf, int mh, half8 (&af)[2][4]) {
    const _Float16* base = &As[buf][mh * 128 + WM * 64][0];
#pragma unroll
    for (int i = 0; i < 4; i++) {
      const int rb = ((i << 4) + fr) << 6;
      af[0][i] = *(const half8*)&base[rb + x0];
      af[1][i] = *(const half8*)&base[rb + x1];
    }
  };
  auto ldsB = [&](int buf, int nh, int j, half8 (&bf)[2]) {
    const _Float16* base = &Bs[buf][nh * 128 + WN * 32 + (j << 4) + fr][0];
    bf[0] = *(const half8*)&base[x0];
    bf[1] = *(const half8*)&base[x1];
  };

  f32x4 acc[2][4][4];  // [mh][i][gate]
#pragma unroll
  for (int a = 0; a < 2; a++)
#pragma unroll
    for (int i = 0; i < 4; i++)
#pragma unroll
      for (int g = 0; g < 4; g++) {
        f32x4 z = {0.f, 0.f, 0.f, 0.f};
        acc[a][i][g] = z;
      }

  // prologue: tile0 fully -> buf0; tile1 A-half0,B-half0 -> buf1 (12 loads in flight)
  stageA(0, 0, 0); stageA(0, 1, 0); stageB(0, 0, 0); stageB(0, 1, 0);
  stageA(1, 0, 1); stageB(1, 0, 1);
  asm volatile("s_waitcnt vmcnt(4)" ::: "memory");   // tile0's 8 loads done
  __builtin_amdgcn_s_barrier();

  for (int t = 0; t < NT; t++) {
    const int cur = t & 1, nxt = cur ^ 1;
    const bool firstHalf = (t < 32);   // gate3 dead in first half, gate2 in second
#pragma unroll
    for (int mh = 0; mh < 2; mh++) {
      half8 af[2][4], b0[2], b1[2], bx[2];
      // ---- phase (mh, nh=0): gates r,z ----
      ldsA(cur, mh, af);
      ldsB(cur, 0, 0, b0);
      ldsB(cur, 0, 1, b1);
      if (mh == 0) { if (t + 1 < NT) stageA(nxt, 1, t + 1); }   // A-half1(t+1)
      else         { if (t + 2 < NT) stageA(cur, 0, t + 2); }   // A-half0(t+2)
      __builtin_amdgcn_s_barrier();
      asm volatile("s_waitcnt lgkmcnt(0)" ::: "memory");
      __builtin_amdgcn_sched_barrier(0);
      __builtin_amdgcn_s_setprio(1);
#pragma unroll
      for (int ks = 0; ks < 2; ks++)
#pragma unroll
        for (int i = 0; i < 4; i++) {
          acc[mh][i][0] = __builtin_amdgcn_mfma_f32_16x16x32_f16(af[ks][i], b0[ks], acc[mh][i][0], 0, 0, 0);
          acc[mh][i][1] = __builtin_amdgcn_mfma_f32_16x16x32_f16(af[ks][i], b1[ks], acc[mh][i][1], 0, 0, 0);
        }
      __builtin_amdgcn_s_setprio(0);
      __builtin_amdgcn_s_barrier();
      // ---- phase (mh, nh=1): live gate only (inn first half, hn second) ----
      ldsB(cur, 1, firstHalf ? 0 : 1, bx);
      if (mh == 0) { if (t + 1 < NT) stageB(nxt, 1, t + 1); }   // B-half1(t+1)
      else         { if (t + 2 < NT) stageB(cur, 0, t + 2); }   // B-half0(t+2)
      __builtin_amdgcn_s_barrier();
      asm volatile("s_waitcnt lgkmcnt(0)" ::: "memory");
      __builtin_amdgcn_sched_barrier(0);
      __builtin_amdgcn_s_setprio(1);
      if (firstHalf) {
#pragma unroll
        for (int ks = 0; ks < 2; ks++)
#pragma unroll
          for (int i = 0; i < 4; i++)
            acc[mh][i][2] = __builtin_amdgcn_mfma_f32_16x16x32_f16(af[ks][i], bx[ks], acc[mh][i][2], 0, 0, 0);
      } else {
#pragma unroll
        for (int ks = 0; ks < 2; ks++)
#pragma unroll
          for (int i = 0; i < 4; i++)
            acc[mh][i][3] = __builtin_amdgcn_mfma_f32_16x16x32_f16(af[ks][i], bx[ks], acc[mh][i][3], 0, 0, 0);
      }
      __builtin_amdgcn_s_setprio(0);
      __builtin_amdgcn_s_barrier();
    }
    // end of K-tile: wait for tile t+1 resident (issue order this iter:
    // Ah1(t+1), Bh1(t+1), Ah0(t+2), Bh0(t+2) -> vmcnt(4) proves t+1 complete)
    if (t + 2 < NT) {
      asm volatile("s_waitcnt vmcnt(4)" ::: "memory");
    } else if (t + 1 < NT) {
      asm volatile("s_waitcnt vmcnt(0)" ::: "memory");
    }
    __builtin_amdgcn_s_barrier();
  }

  // ---- GRU epilogue: lane owns h-col c, all 4 gates ----
  const int c = blockIdx.x * 64 + WN * 16 + fr;
  if (c >= H) return;
  const float b_r = b_ih[c] + b_hh[c];
  const float b_z = b_ih[H + c] + b_hh[H + c];
  const float b_in = b_ih[2 * H + c];
  const float b_hn = b_hh[2 * H + c];
#pragma unroll
  for (int mh = 0; mh < 2; mh++)
#pragma unroll
    for (int i = 0; i < 4; i++)
#pragma unroll
      for (int r = 0; r < 4; r++) {
        int m = bm + mh * 128 + WM * 64 + i * 16 + quad * 4 + r;
        float rg = 1.f / (1.f + expf(-(acc[mh][i][0][r] + b_r)));
        float zg = 1.f / (1.f + expf(-(acc[mh][i][1][r] + b_z)));
        float nn = tanhf(acc[mh][i][2][r] + b_in + rg * (acc[mh][i][3][r] + b_hn));
        float hold = (float)Hc[(size_t)m * SEG + c];
        Hn[(size_t)m * SEG + c] = (_Float16)((1.f - zg) * nn + zg * hold);
      }
}

// ---------------- relu + segment max pool (fp16 in, fp32 out) ----------------
__global__ void pool16_kernel(const _Float16* __restrict__ h, const int* __restrict__ starts,
                              float* __restrict__ pooled) {
  int b = blockIdx.x;
  int s = starts[b], e = starts[b + 1];
  for (int idx = threadIdx.x; idx < H; idx += 256) {
    float mx = 0.f;  // relu floor
    for (int n = s; n < e; n++) mx = fmaxf(mx, (float)h[(size_t)n * SEG + idx]);
    pooled[b * H + idx] = mx;
  }
}

// ---------------- conv / linear tail (fp32) ----------------
__global__ void conv1_kernel(const float* __restrict__ in, const float* __restrict__ w,
                             const float* __restrict__ bias, float* __restrict__ outp) {
  __shared__ float sin_[H];
  int b = blockIdx.x;
  for (int j = threadIdx.x; j < H; j += 256) sin_[j] = in[(size_t)b * H + j];
  __syncthreads();
  for (int idx = threadIdx.x; idx < C1_OC * C1_L; idx += 256) {
    int oc = idx / C1_L, t = idx % C1_L;
    float w0 = w[oc * 3], w1 = w[oc * 3 + 1], w2 = w[oc * 3 + 2];
    float bb = bias[oc];
    float best = 0.f;
    int base = t * 3;
#pragma unroll
    for (int p = 0; p < 3; p++) {
      float v = fmaf(sin_[base + p], w0, fmaf(sin_[base + p + 1], w1,
                fmaf(sin_[base + p + 2], w2, bb)));
      best = fmaxf(best, v);
    }
    outp[((size_t)b * C1_OC + oc) * C1_L + t] = best;
  }
}

__global__ void conv2_kernel(const float* __restrict__ in, const float* __restrict__ w,
                             const float* __restrict__ bias, float* __restrict__ outp) {
  int idx = blockIdx.x * 256 + threadIdx.x;
  if (idx >= NB * C2_OC * C2_L) return;
  int t = idx % C2_L;
  int rem = idx / C2_L;
  int oc = rem % C2_OC;
  int b = rem / C2_OC;
  const float* ip = in + (size_t)b * C1_OC * C1_L;
  const float* wp = w + oc * C1_OC * 3;
  float bb = bias[oc];
  float s0 = bb, s1 = bb, s2 = bb;
  int tc = t * 3;
  for (int ic = 0; ic < C1_OC; ic++) {
    const float* r = ip + ic * C1_L + tc;
    float v0 = r[0], v1 = r[1], v2 = r[2], v3 = r[3], v4 = r[4];
    float w0 = wp[ic * 3], w1 = wp[ic * 3 + 1], w2 = wp[ic * 3 + 2];
    s0 = fmaf(v0, w0, fmaf(v1, w1, fmaf(v2, w2, s0)));
    s1 = fmaf(v1, w0, fmaf(v2, w1, fmaf(v3, w2, s1)));
    s2 = fmaf(v2, w0, fmaf(v3, w1, fmaf(v4, w2, s2)));
  }
  outp[idx] = fmaxf(fmaxf(s0, fmaxf(s1, s2)), 0.f);
}

__global__ void conv3_kernel(const float* __restrict__ in, const float* __restrict__ w,
                             const float* __restrict__ bias, float* __restrict__ outp) {
  int idx = blockIdx.x * 256 + threadIdx.x;
  if (idx >= NB * C3_OC * C3_L) return;
  int t = idx % C3_L;
  int rem = idx / C3_L;
  int oc = rem % C3_OC;
  int b = rem / C3_OC;
  const float* ip = in + (size_t)b * C2_OC * C2_L;
  const float* wp = w + oc * C2_OC * 3;
  float bb = bias[oc];
  float s0 = bb, s1 = bb, s2 = bb;
  int tc = t * 3;
  for (int ic = 0; ic < C2_OC; ic++) {
    const float* r = ip + ic * C2_L + tc;
    float v0 = r[0], v1 = r[1], v2 = r[2], v3 = r[3], v4 = r[4];
    float w0 = wp[ic * 3], w1 = wp[ic * 3 + 1], w2 = wp[ic * 3 + 2];
    s0 = fmaf(v0, w0, fmaf(v1, w1, fmaf(v2, w2, s0)));
    s1 = fmaf(v1, w0, fmaf(v2, w1, fmaf(v3, w2, s1)));
    s2 = fmaf(v2, w0, fmaf(v3, w1, fmaf(v4, w2, s2)));
  }
  outp[idx] = fmaxf(fmaxf(s0, fmaxf(s1, s2)), 0.f);
}

__global__ void lin1_kernel(const float* __restrict__ x, const float* __restrict__ w,
                            const float* __restrict__ bias, float* __restrict__ outp) {
  int gid = blockIdx.x * 4 + (threadIdx.x >> 6);
  int lane = threadIdx.x & 63;
  int b = gid / LIN1_OUT;
  int o = gid % LIN1_OUT;
  const float* xp = x + (size_t)b * LIN1_IN;
  const float* wp = w + (size_t)o * LIN1_IN;
  float s = 0.f;
  for (int k = lane; k < LIN1_IN; k += 64) s = fmaf(xp[k], wp[k], s);
#pragma unroll
  for (int off = 32; off > 0; off >>= 1) s += __shfl_down(s, off, 64);
  if (lane == 0) outp[b * LIN1_OUT + o] = fmaxf(s + bias[o], 0.f);
}

__global__ void lin2_kernel(const float* __restrict__ x, const float* __restrict__ w,
                            const float* __restrict__ bias, float* __restrict__ outp) {
  int tid = threadIdx.x;
  int b = tid >> 2, o = tid & 3;
  const float* xp = x + b * LIN1_OUT;
  const float* wp = w + o * LIN1_OUT;
  float s = bias[o];
  for (int k = 0; k < LIN1_OUT; k++) s = fmaf(xp[k], wp[k], s);
  outp[b * 4 + o] = fmaxf(s, 0.f);
}

// ================= launch =================
extern "C" void kernel_launch(void* const* d_in, const int* in_sizes, int n_in,
                              void* d_out, int out_size, void* d_ws, size_t ws_size,
                              hipStream_t stream) {
  const int* tokens = (const int*)d_in[0];
  const int* edge_index = (const int*)d_in[1];
  const int* batch = (const int*)d_in[2];
  const float* embed = (const float*)d_in[3];
  const float* W_ggc = (const float*)d_in[4];
  const float* W_ih = (const float*)d_in[5];
  const float* W_hh = (const float*)d_in[6];
  const float* b_ih = (const float*)d_in[7];
  const float* b_hh = (const float*)d_in[8];
  const float* c1w = (const float*)d_in[9];
  const float* c1b = (const float*)d_in[10];
  const float* c2w = (const float*)d_in[11];
  const float* c2b = (const float*)d_in[12];
  const float* c3w = (const float*)d_in[13];
  const float* c3b = (const float*)d_in[14];
  const float* l1w = (const float*)d_in[15];
  const float* l1b = (const float*)d_in[16];
  const float* l2w = (const float*)d_in[17];
  const float* l2b = (const float*)d_in[18];
  float* out = (float*)d_out;

  const int* e_src = edge_index;
  const int* e_dst = edge_index + N_EDGES;

  char* ws = (char*)d_ws;
  size_t off = 0;
  auto alloc = [&](size_t bytes) -> void* {
    void* p = ws + off;
    off = (off + bytes + 255) & ~(size_t)255;
    return p;
  };

  const size_t ACT = sizeof(_Float16) * (size_t)MP * SEG;   // 41.9 MB
  _Float16* bufX = (_Float16*)alloc(ACT);                   // h (current)
  _Float16* bufY = (_Float16*)alloc(ACT);                   // m / h_next (rotates with X)
  _Float16* bufZ = (_Float16*)alloc(ACT);                   // agg (fixed)
  _Float16* Wg_b = (_Float16*)alloc(sizeof(_Float16) * (size_t)LAYERS * NW * SEG);  // 33.5 MB
  _Float16* Wp   = (_Float16*)alloc(sizeof(_Float16) * (size_t)NPACK * KK2);        // 67 MB
  int* counts = (int*)alloc(sizeof(int) * (N_NODES + 1));
  int* row_off = (int*)alloc(sizeof(int) * (N_NODES + 1));
  int* cursor = (int*)alloc(sizeof(int) * N_NODES);
  int* csr_src = (int*)alloc(sizeof(int) * N_EDGES);
  int* starts = (int*)alloc(sizeof(int) * (NB + 1));

  // tail buffers alias bufZ (agg dead after last gru): 17.6 MB < 41.9 MB
  char* tb = (char*)bufZ;
  size_t toff = 0;
  auto talloc = [&](size_t bytes) -> void* {
    void* p = tb + toff;
    toff = (toff + bytes + 255) & ~(size_t)255;
    return p;
  };
  float* pooled = (float*)talloc(sizeof(float) * NB * H);
  float* c1 = (float*)talloc(sizeof(float) * (size_t)NB * C1_OC * C1_L);
  float* c2 = (float*)talloc(sizeof(float) * (size_t)NB * C2_OC * C2_L);
  float* c3 = (float*)talloc(sizeof(float) * (size_t)NB * C3_OC * C3_L);
  float* l1out = (float*)talloc(sizeof(float) * NB * LIN1_OUT);

  hipMemsetAsync(counts, 0, sizeof(int) * (N_NODES + 1), stream);
  hipMemsetAsync(cursor, 0, sizeof(int) * N_NODES, stream);

  // weight prep
  {
    dim3 gg(SEG / 32, NW / 32, LAYERS);
    prep_wg16_kernel<<<gg, 256, 0, stream>>>(W_ggc, Wg_b);
    dim3 gp(KK2 / 256, NPACK);
    prep_wpack_kernel<<<gp, 256, 0, stream>>>(W_ih, W_hh, Wp);
  }

  embed16_kernel<<<N_NODES, 256, 0, stream>>>(tokens, embed, bufX);
  hist_kernel<<<(N_EDGES + 255) / 256, 256, 0, stream>>>(e_dst, counts, N_EDGES);
  scan_kernel<<<1, 1024, 0, stream>>>(counts, row_off, N_NODES);
  scatter_kernel<<<(N_EDGES + 255) / 256, 256, 0, stream>>>(e_src, e_dst, row_off, cursor,
                                                            csr_src, N_EDGES);
  starts_kernel<<<(N_NODES + 255) / 256, 256, 0, stream>>>(batch, starts, N_NODES);

  dim3 grid_m(NW / 128, MP / 128);          // 16 x 80
  dim3 grid_gru(NPACK / 256, MP / 256);     // 32 x 40
  _Float16* X = bufX;
  _Float16* Y = bufY;
  for (int l = 0; l < LAYERS; l++) {
    gemm16_kernel<<<grid_m, 256, 0, stream>>>(X, Wg_b + (size_t)l * NW * SEG, Y);
    agg16_kernel<<<N_NODES, 256, 0, stream>>>(Y, row_off, csr_src, bufZ);
    gru8p_kernel<<<grid_gru, 512, 0, stream>>>(bufZ, X, Wp, b_ih, b_hh, Y);
    _Float16* t = X; X = Y; Y = t;
  }
  // X holds final h

  pool16_kernel<<<NB, 256, 0, stream>>>(X, starts, pooled);
  conv1_kernel<<<NB, 256, 0, stream>>>(pooled, c1w, c1b, c1);
  conv2_kernel<<<(NB * C2_OC * C2_L + 255) / 256, 256, 0, stream>>>(c1, c2w, c2b, c2);
  conv3_kernel<<<(NB * C3_OC * C3_L + 255) / 256, 256, 0, stream>>>(c2, c3w, c3b, c3);
  lin1_kernel<<<NB * LIN1_OUT / 4, 256, 0, stream>>>(c3, l1w, l1b, l1out);
  lin2_kernel<<<1, 256, 0, stream>>>(l1out, l2w, l2b, out);
}